// Round 3
// baseline (2167.463 us; speedup 1.0000x reference)
//
#include <hip/hip_runtime.h>

#define WW 512
#define HH 512
#define STRIP 64

// Gaussian sigma=1, k=7, normalized
#define G0 0.39905028f
#define G1 0.24203623f
#define G2 0.05400558f
#define G3 0.00443305f

typedef unsigned short u16;
typedef unsigned int u32;

__device__ __forceinline__ float b2f_lo(u32 u) {
  union { u32 i; float f; } v; v.i = u << 16; return v.f;
}
__device__ __forceinline__ float b2f_hi(u32 u) {
  union { u32 i; float f; } v; v.i = u & 0xffff0000u; return v.f;
}
__device__ __forceinline__ float b2f(u16 u) {
  union { u32 i; float f; } v; v.i = ((u32)u) << 16; return v.f;
}

__device__ __forceinline__ int reflect_idx(int i) {
  i = (i < 0) ? -i : i;
  return (i >= WW) ? (2 * WW - 2 - i) : i;
}

// Load cols c0-3 .. c0+4 of row `rowp` into x[0..7] as fp32.
template <typename T>
__device__ __forceinline__ void load8(const T* __restrict__ rowp, int c0, bool edge,
                                      float* __restrict__ x) {
  if constexpr (sizeof(T) == 2) {  // bf16 storage
    if (!edge) {
      const u32* p = reinterpret_cast<const u32*>(rowp + (c0 - 4));
      u32 v0 = p[0], v1 = p[1], v2 = p[2], v3 = p[3], v4 = p[4];
      x[0] = b2f_hi(v0);
      x[1] = b2f_lo(v1); x[2] = b2f_hi(v1);
      x[3] = b2f_lo(v2); x[4] = b2f_hi(v2);
      x[5] = b2f_lo(v3); x[6] = b2f_hi(v3);
      x[7] = b2f_lo(v4);
    } else {
#pragma unroll
      for (int m = 0; m < 8; ++m) x[m] = b2f(rowp[reflect_idx(c0 - 3 + m)]);
    }
  } else {  // fp32 storage
    if (!edge) {
      const float2* p = reinterpret_cast<const float2*>(rowp + (c0 - 4));
      float2 v0 = p[0], v1 = p[1], v2 = p[2], v3 = p[3], v4 = p[4];
      x[0] = v0.y;
      x[1] = v1.x; x[2] = v1.y;
      x[3] = v2.x; x[4] = v2.y;
      x[5] = v3.x; x[6] = v3.y;
      x[7] = v4.x;
    } else {
#pragma unroll
      for (int m = 0; m < 8; ++m) x[m] = (float)rowp[reflect_idx(c0 - 3 + m)];
    }
  }
}

// Horizontal 7-tap blur of pre-loaded x (cols c0-3..c0+4) at cols c0, c0+1.
__device__ __forceinline__ void hblur(const float* __restrict__ x,
                                      float* __restrict__ h, float* __restrict__ h2) {
  h[0] = G3 * (x[0] + x[6]) + G2 * (x[1] + x[5]) + G1 * (x[2] + x[4]) + G0 * x[3];
  h[1] = G3 * (x[1] + x[7]) + G2 * (x[2] + x[6]) + G1 * (x[3] + x[5]) + G0 * x[4];
  float q[8];
#pragma unroll
  for (int m = 0; m < 8; ++m) q[m] = x[m] * x[m];
  h2[0] = G3 * (q[0] + q[6]) + G2 * (q[1] + q[5]) + G1 * (q[2] + q[4]) + G0 * q[3];
  h2[1] = G3 * (q[1] + q[7]) + G2 * (q[2] + q[6]) + G1 * (q[3] + q[5]) + G0 * q[4];
}

// Vertical 7-tap combine + AdaIN epilogue for output row ro; window slot phase j.
template <typename T>
__device__ __forceinline__ void emit_out(const T* __restrict__ cp,
                                         float* __restrict__ op,
                                         int ro, int c0, int j,
                                         const float wc[7][2], const float wc2[7][2],
                                         const float ws[7][2], const float ws2[7][2]) {
  constexpr float Gv[7] = {G3, G2, G1, G0, G1, G2, G3};
  float cm0 = 0.f, cm1 = 0.f, cq0 = 0.f, cq1 = 0.f;
  float sm0 = 0.f, sm1 = 0.f, sq0 = 0.f, sq1 = 0.f;
#pragma unroll
  for (int m = 0; m < 7; ++m) {
    const int s = (j + 1 + m) % 7;  // compile-time when j,m compile-time
    const float gm = Gv[m];
    cm0 += gm * wc[s][0];  cm1 += gm * wc[s][1];
    cq0 += gm * wc2[s][0]; cq1 += gm * wc2[s][1];
    sm0 += gm * ws[s][0];  sm1 += gm * ws[s][1];
    sq0 += gm * ws2[s][0]; sq1 += gm * ws2[s][1];
  }
  const float cv0 = fmaxf(cq0 - cm0 * cm0, 0.f);
  const float cv1 = fmaxf(cq1 - cm1 * cm1, 0.f);
  const float sv0 = fmaxf(sq0 - sm0 * sm0, 0.f);
  const float sv1 = fmaxf(sq1 - sm1 * sm1, 0.f);
  const float cs0 = __builtin_amdgcn_sqrtf(cv0) + 1e-5f;
  const float cs1 = __builtin_amdgcn_sqrtf(cv1) + 1e-5f;
  const float ss0 = __builtin_amdgcn_sqrtf(sv0) + 1e-5f;
  const float ss1 = __builtin_amdgcn_sqrtf(sv1) + 1e-5f;
  // reload content center pair (row is L1/L2-hot)
  float x0, x1;
  if constexpr (sizeof(T) == 2) {
    const u32 xc = *reinterpret_cast<const u32*>(cp + ro * WW + c0);
    x0 = b2f_lo(xc);
    x1 = b2f_hi(xc);
  } else {
    const float2 xc = *reinterpret_cast<const float2*>(cp + ro * WW + c0);
    x0 = xc.x;
    x1 = xc.y;
  }
  float2 o;
  o.x = (x0 - cm0) * ss0 * __builtin_amdgcn_rcpf(cs0) + sm0;
  o.y = (x1 - cm1) * ss1 * __builtin_amdgcn_rcpf(cs1) + sm1;
  *reinterpret_cast<float2*>(op + ro * WW + c0) = o;  // fp32 output, always
}

// Software-pipelined plane walker: loads for row i+1 issue before the
// vertical+epilogue of output row i-6, hiding load latency under ~90 VALU ops.
template <typename T>
__device__ __forceinline__ void run_plane(const T* __restrict__ cp,
                                          const T* __restrict__ sp,
                                          float* __restrict__ op,
                                          int r0, int c0, bool edge) {
  float wc[7][2], wc2[7][2], ws[7][2], ws2[7][2];
  float xc[8], xs[8];

  // prologue: load row i=0 (global row reflect(r0-3))
  load8<T>(cp + reflect_idx(r0 - 3) * WW, c0, edge, xc);
  load8<T>(sp + reflect_idx(r0 - 3) * WW, c0, edge, xs);

  // ii = 0 : rows 0..6; first output at i=6 (j==6)
#pragma unroll
  for (int j = 0; j < 7; ++j) {
    hblur(xc, wc[j], wc2[j]);
    hblur(xs, ws[j], ws2[j]);
    const int gr = reflect_idx(r0 - 3 + j + 1);  // row i+1, always exists here
    load8<T>(cp + gr * WW, c0, edge, xc);
    load8<T>(sp + gr * WW, c0, edge, xs);
    if (j == 6) emit_out<T>(cp, op, r0, c0, j, wc, wc2, ws, ws2);
  }

  // main: ii = 1..8 — every j emits an output; prefetch row i+1
#pragma unroll 1
  for (int ii = 1; ii < 9; ++ii) {
#pragma unroll
    for (int j = 0; j < 7; ++j) {
      const int i_lin = ii * 7 + j;           // row index in [7,62]
      hblur(xc, wc[j], wc2[j]);
      hblur(xs, ws[j], ws2[j]);
      const int gr = reflect_idx(r0 - 3 + i_lin + 1);
      load8<T>(cp + gr * WW, c0, edge, xc);
      load8<T>(sp + gr * WW, c0, edge, xs);
      emit_out<T>(cp, op, r0 + i_lin - 6, c0, j, wc, wc2, ws, ws2);
    }
  }

  // epilogue: ii = 9 — rows 63..69; no prefetch past row 69
#pragma unroll
  for (int j = 0; j < 7; ++j) {
    const int i_lin = 63 + j;
    hblur(xc, wc[j], wc2[j]);
    hblur(xs, ws[j], ws2[j]);
    if (j < 6) {
      const int gr = reflect_idx(r0 - 3 + i_lin + 1);
      load8<T>(cp + gr * WW, c0, edge, xc);
      load8<T>(sp + gr * WW, c0, edge, xs);
    }
    emit_out<T>(cp, op, r0 + i_lin - 6, c0, j, wc, wc2, ws, ws2);
  }
}

// Detect input storage dtype. Genuine fp32 N(0,1) values have biased exponent
// in [100,151] essentially always; bf16 pairs read as fp32 essentially never.
__global__ void detect_dtype(const u32* __restrict__ x, int* __restrict__ flag) {
  const int lane = threadIdx.x;
  const u32 u = x[lane * 997 + 13];
  const int e = (int)((u >> 23) & 0xffu);
  const bool sane = (e >= 100) && (e <= 151);
  const unsigned long long m = __ballot(sane);
  if (lane == 0) *flag = (__popcll(m) >= 32) ? 1 : 0;
}

// Split kernels: each instantiates ONE dtype path so VGPR allocation is not
// the max over both. The non-matching kernel early-exits (launch-cost only).
// __launch_bounds__(256, 4): force VGPR<=128 -> 4 blocks/CU (occupancy cliff
// at 128 VGPRs: 129-256 regs would halve waves/SIMD to 2). If counters show
// scratch spills + regression, revert to (256).
__global__ void __launch_bounds__(256, 4) adain_f32(
    const float* __restrict__ content, const float* __restrict__ style,
    float* __restrict__ out, const int* __restrict__ flag) {
  if (!*flag) return;  // inputs are bf16 -> not ours
  const int tid = threadIdx.x;
  const int c0 = tid << 1;
  const bool edge = (c0 < 4) || (c0 > WW - 6);
  const int r0 = blockIdx.x * STRIP;
  const long long base = (long long)blockIdx.y * (HH * WW);
  run_plane<float>(content + base, style + base, out + base, r0, c0, edge);
}

__global__ void __launch_bounds__(256, 4) adain_bf16(
    const u16* __restrict__ content, const u16* __restrict__ style,
    float* __restrict__ out, const int* __restrict__ flag) {
  if (*flag) return;  // inputs are fp32 -> not ours
  const int tid = threadIdx.x;
  const int c0 = tid << 1;
  const bool edge = (c0 < 4) || (c0 > WW - 6);
  const int r0 = blockIdx.x * STRIP;
  const long long base = (long long)blockIdx.y * (HH * WW);
  run_plane<u16>(content + base, style + base, out + base, r0, c0, edge);
}

extern "C" void kernel_launch(void* const* d_in, const int* in_sizes, int n_in,
                              void* d_out, int out_size, void* d_ws, size_t ws_size,
                              hipStream_t stream) {
  const void* content = d_in[0];
  const void* style = d_in[1];
  float* out = (float*)d_out;
  int* flag = (int*)d_ws;
  detect_dtype<<<1, 64, 0, stream>>>((const u32*)content, flag);
  const int planes = out_size / (HH * WW);  // B*C = 256
  dim3 grid(HH / STRIP, planes);            // (8, 256)
  adain_f32<<<grid, 256, 0, stream>>>((const float*)content, (const float*)style, out, flag);
  adain_bf16<<<grid, 256, 0, stream>>>((const u16*)content, (const u16*)style, out, flag);
}

// Round 7
// 1018.015 us; speedup vs baseline: 2.1291x; 2.1291x over previous
//
#include <hip/hip_runtime.h>

#define WW 512
#define HH 512
#define STRIP 64

// Gaussian sigma=1, k=7, normalized
#define G0 0.39905028f
#define G1 0.24203623f
#define G2 0.05400558f
#define G3 0.00443305f

typedef unsigned short u16;
typedef unsigned int u32;

__device__ __forceinline__ float b2f_lo(u32 u) {
  union { u32 i; float f; } v; v.i = u << 16; return v.f;
}
__device__ __forceinline__ float b2f_hi(u32 u) {
  union { u32 i; float f; } v; v.i = u & 0xffff0000u; return v.f;
}
__device__ __forceinline__ float b2f(u16 u) {
  union { u32 i; float f; } v; v.i = ((u32)u) << 16; return v.f;
}

__device__ __forceinline__ int reflect_idx(int i) {
  i = (i < 0) ? -i : i;
  return (i >= WW) ? (2 * WW - 2 - i) : i;
}

// Load cols c0-3 .. c0+4 of row `rowp` into x[0..7] as fp32.
template <typename T>
__device__ __forceinline__ void load8(const T* __restrict__ rowp, int c0, bool edge,
                                      float* __restrict__ x) {
  if constexpr (sizeof(T) == 2) {  // bf16 storage
    if (!edge) {
      const u32* p = reinterpret_cast<const u32*>(rowp + (c0 - 4));
      u32 v0 = p[0], v1 = p[1], v2 = p[2], v3 = p[3], v4 = p[4];
      x[0] = b2f_hi(v0);
      x[1] = b2f_lo(v1); x[2] = b2f_hi(v1);
      x[3] = b2f_lo(v2); x[4] = b2f_hi(v2);
      x[5] = b2f_lo(v3); x[6] = b2f_hi(v3);
      x[7] = b2f_lo(v4);
    } else {
#pragma unroll
      for (int m = 0; m < 8; ++m) x[m] = b2f(rowp[reflect_idx(c0 - 3 + m)]);
    }
  } else {  // fp32 storage
    if (!edge) {
      const float2* p = reinterpret_cast<const float2*>(rowp + (c0 - 4));
      float2 v0 = p[0], v1 = p[1], v2 = p[2], v3 = p[3], v4 = p[4];
      x[0] = v0.y;
      x[1] = v1.x; x[2] = v1.y;
      x[3] = v2.x; x[4] = v2.y;
      x[5] = v3.x; x[6] = v3.y;
      x[7] = v4.x;
    } else {
#pragma unroll
      for (int m = 0; m < 8; ++m) x[m] = (float)rowp[reflect_idx(c0 - 3 + m)];
    }
  }
}

// Horizontal 7-tap blur of pre-loaded x (cols c0-3..c0+4) at cols c0, c0+1.
__device__ __forceinline__ void hblur(const float* __restrict__ x,
                                      float* __restrict__ h, float* __restrict__ h2) {
  h[0] = G3 * (x[0] + x[6]) + G2 * (x[1] + x[5]) + G1 * (x[2] + x[4]) + G0 * x[3];
  h[1] = G3 * (x[1] + x[7]) + G2 * (x[2] + x[6]) + G1 * (x[3] + x[5]) + G0 * x[4];
  float q[8];
#pragma unroll
  for (int m = 0; m < 8; ++m) q[m] = x[m] * x[m];
  h2[0] = G3 * (q[0] + q[6]) + G2 * (q[1] + q[5]) + G1 * (q[2] + q[4]) + G0 * q[3];
  h2[1] = G3 * (q[1] + q[7]) + G2 * (q[2] + q[6]) + G1 * (q[3] + q[5]) + G0 * q[4];
}

// Vertical 7-tap combine + AdaIN epilogue for output row ro; window slot phase j.
template <typename T>
__device__ __forceinline__ void emit_out(const T* __restrict__ cp,
                                         float* __restrict__ op,
                                         int ro, int c0, int j,
                                         const float wc[7][2], const float wc2[7][2],
                                         const float ws[7][2], const float ws2[7][2]) {
  constexpr float Gv[7] = {G3, G2, G1, G0, G1, G2, G3};
  float cm0 = 0.f, cm1 = 0.f, cq0 = 0.f, cq1 = 0.f;
  float sm0 = 0.f, sm1 = 0.f, sq0 = 0.f, sq1 = 0.f;
#pragma unroll
  for (int m = 0; m < 7; ++m) {
    const int s = (j + 1 + m) % 7;  // compile-time when j,m compile-time
    const float gm = Gv[m];
    cm0 += gm * wc[s][0];  cm1 += gm * wc[s][1];
    cq0 += gm * wc2[s][0]; cq1 += gm * wc2[s][1];
    sm0 += gm * ws[s][0];  sm1 += gm * ws[s][1];
    sq0 += gm * ws2[s][0]; sq1 += gm * ws2[s][1];
  }
  const float cv0 = fmaxf(cq0 - cm0 * cm0, 0.f);
  const float cv1 = fmaxf(cq1 - cm1 * cm1, 0.f);
  const float sv0 = fmaxf(sq0 - sm0 * sm0, 0.f);
  const float sv1 = fmaxf(sq1 - sm1 * sm1, 0.f);
  const float cs0 = __builtin_amdgcn_sqrtf(cv0) + 1e-5f;
  const float cs1 = __builtin_amdgcn_sqrtf(cv1) + 1e-5f;
  const float ss0 = __builtin_amdgcn_sqrtf(sv0) + 1e-5f;
  const float ss1 = __builtin_amdgcn_sqrtf(sv1) + 1e-5f;
  // reload content center pair (row is L1/L2-hot)
  float x0, x1;
  if constexpr (sizeof(T) == 2) {
    const u32 xc = *reinterpret_cast<const u32*>(cp + ro * WW + c0);
    x0 = b2f_lo(xc);
    x1 = b2f_hi(xc);
  } else {
    const float2 xc = *reinterpret_cast<const float2*>(cp + ro * WW + c0);
    x0 = xc.x;
    x1 = xc.y;
  }
  float2 o;
  o.x = (x0 - cm0) * ss0 * __builtin_amdgcn_rcpf(cs0) + sm0;
  o.y = (x1 - cm1) * ss1 * __builtin_amdgcn_rcpf(cs1) + sm1;
  *reinterpret_cast<float2*>(op + ro * WW + c0) = o;  // fp32 output, always
}

// Software-pipelined plane walker: loads for row i+1 issue before the
// vertical+epilogue of output row i-6, hiding load latency under ~90 VALU ops.
template <typename T>
__device__ __forceinline__ void run_plane(const T* __restrict__ cp,
                                          const T* __restrict__ sp,
                                          float* __restrict__ op,
                                          int r0, int c0, bool edge) {
  float wc[7][2], wc2[7][2], ws[7][2], ws2[7][2];
  float xc[8], xs[8];

  // prologue: load row i=0 (global row reflect(r0-3))
  load8<T>(cp + reflect_idx(r0 - 3) * WW, c0, edge, xc);
  load8<T>(sp + reflect_idx(r0 - 3) * WW, c0, edge, xs);

  // ii = 0 : rows 0..6; first output at i=6 (j==6)
#pragma unroll
  for (int j = 0; j < 7; ++j) {
    hblur(xc, wc[j], wc2[j]);
    hblur(xs, ws[j], ws2[j]);
    const int gr = reflect_idx(r0 - 3 + j + 1);  // row i+1, always exists here
    load8<T>(cp + gr * WW, c0, edge, xc);
    load8<T>(sp + gr * WW, c0, edge, xs);
    if (j == 6) emit_out<T>(cp, op, r0, c0, j, wc, wc2, ws, ws2);
  }

  // main: ii = 1..8 — every j emits an output; prefetch row i+1
#pragma unroll 1
  for (int ii = 1; ii < 9; ++ii) {
#pragma unroll
    for (int j = 0; j < 7; ++j) {
      const int i_lin = ii * 7 + j;           // row index in [7,62]
      hblur(xc, wc[j], wc2[j]);
      hblur(xs, ws[j], ws2[j]);
      const int gr = reflect_idx(r0 - 3 + i_lin + 1);
      load8<T>(cp + gr * WW, c0, edge, xc);
      load8<T>(sp + gr * WW, c0, edge, xs);
      emit_out<T>(cp, op, r0 + i_lin - 6, c0, j, wc, wc2, ws, ws2);
    }
  }

  // epilogue: ii = 9 — rows 63..69; no prefetch past row 69
#pragma unroll
  for (int j = 0; j < 7; ++j) {
    const int i_lin = 63 + j;
    hblur(xc, wc[j], wc2[j]);
    hblur(xs, ws[j], ws2[j]);
    if (j < 6) {
      const int gr = reflect_idx(r0 - 3 + i_lin + 1);
      load8<T>(cp + gr * WW, c0, edge, xc);
      load8<T>(sp + gr * WW, c0, edge, xs);
    }
    emit_out<T>(cp, op, r0 + i_lin - 6, c0, j, wc, wc2, ws, ws2);
  }
}

// Detect input storage dtype. Genuine fp32 N(0,1) values have biased exponent
// in [100,151] essentially always; bf16 pairs read as fp32 essentially never.
__global__ void detect_dtype(const u32* __restrict__ x, int* __restrict__ flag) {
  const int lane = threadIdx.x;
  const u32 u = x[lane * 997 + 13];
  const int e = (int)((u >> 23) & 0xffu);
  const bool sane = (e >= 100) && (e <= 151);
  const unsigned long long m = __ballot(sane);
  if (lane == 0) *flag = (__popcll(m) >= 32) ? 1 : 0;
}

// Split kernels: each instantiates ONE dtype path so VGPR allocation is not
// the max over both. The non-matching kernel early-exits (launch-cost only).
// NOTE (R3 post-mortem): __launch_bounds__(256, 4) made the allocator jump to
// 64 VGPRs and spill the 56-float sliding window to scratch: WRITE_SIZE 8x
// ideal, VALUBusy 9%, dur 1790us. Natural allocation (~130-170 VGPRs,
// 2-3 waves/SIMD) is the right point for this kernel. Do NOT re-add min-waves.
__global__ void __launch_bounds__(256) adain_f32(
    const float* __restrict__ content, const float* __restrict__ style,
    float* __restrict__ out, const int* __restrict__ flag) {
  if (!*flag) return;  // inputs are bf16 -> not ours
  const int tid = threadIdx.x;
  const int c0 = tid << 1;
  const bool edge = (c0 < 4) || (c0 > WW - 6);
  const int r0 = blockIdx.x * STRIP;
  const long long base = (long long)blockIdx.y * (HH * WW);
  run_plane<float>(content + base, style + base, out + base, r0, c0, edge);
}

__global__ void __launch_bounds__(256) adain_bf16(
    const u16* __restrict__ content, const u16* __restrict__ style,
    float* __restrict__ out, const int* __restrict__ flag) {
  if (*flag) return;  // inputs are fp32 -> not ours
  const int tid = threadIdx.x;
  const int c0 = tid << 1;
  const bool edge = (c0 < 4) || (c0 > WW - 6);
  const int r0 = blockIdx.x * STRIP;
  const long long base = (long long)blockIdx.y * (HH * WW);
  run_plane<u16>(content + base, style + base, out + base, r0, c0, edge);
}

extern "C" void kernel_launch(void* const* d_in, const int* in_sizes, int n_in,
                              void* d_out, int out_size, void* d_ws, size_t ws_size,
                              hipStream_t stream) {
  const void* content = d_in[0];
  const void* style = d_in[1];
  float* out = (float*)d_out;
  int* flag = (int*)d_ws;
  detect_dtype<<<1, 64, 0, stream>>>((const u32*)content, flag);
  const int planes = out_size / (HH * WW);  // B*C = 256
  dim3 grid(HH / STRIP, planes);            // (8, 256)
  adain_f32<<<grid, 256, 0, stream>>>((const float*)content, (const float*)style, out, flag);
  adain_bf16<<<grid, 256, 0, stream>>>((const u16*)content, (const u16*)style, out, flag);
}